// Round 6
// baseline (31464.304 us; speedup 1.0000x reference)
//
#include <hip/hip_runtime.h>
#include <cstdint>

#define T_STEPS 8192
#define HDIM    1024

typedef float        f32x4 __attribute__((ext_vector_type(4)));
typedef unsigned int u32x4 __attribute__((ext_vector_type(4)));

__device__ __forceinline__ float dot4(f32x4 a, f32x4 b) {
    return a[0] * b[0] + a[1] * b[1] + a[2] * b[2] + a[3] * b[3];
}
__device__ __forceinline__ float sigmoidf_(float v) { return 1.0f / (1.0f + __expf(-v)); }
__device__ __forceinline__ float tanhf_(float v)    { return 1.0f - 2.0f / (__expf(2.0f * v) + 1.0f); }

// ================= phase 1: gxT[b][t][q*4+w] = x[t]·W_ih[1024q+4b+w] + bias =================
// (verbatim from R4 — correctness-proven)
__global__ __launch_bounds__(256)
void gemm_gx(const float* __restrict__ x, const float* __restrict__ W_ih,
             const float* __restrict__ b_ih, const float* __restrict__ b_hh,
             float* __restrict__ gxT)
{
    __shared__ float a_s[16][68];
    __shared__ float b_s[16][68];
    const int t  = threadIdx.x;
    const int bm = blockIdx.x >> 6;
    const int bn = blockIdx.x & 63;
    const int m0 = bm << 6, n0 = bn << 6;
    const int tx = t & 15, ty = t >> 4;
    const int lm = t >> 2;
    const int lk = (t & 3) << 2;

    float acc[4][4] = {};
    for (int k0 = 0; k0 < 1024; k0 += 16) {
        f32x4 av = *(const f32x4*)(x    + (size_t)(m0 + lm) * 1024 + k0 + lk);
        f32x4 bv = *(const f32x4*)(W_ih + (size_t)(n0 + lm) * 1024 + k0 + lk);
        __syncthreads();
#pragma unroll
        for (int j = 0; j < 4; ++j) { a_s[lk + j][lm] = av[j]; b_s[lk + j][lm] = bv[j]; }
        __syncthreads();
#pragma unroll
        for (int k = 0; k < 16; ++k) {
            f32x4 af = *(const f32x4*)&a_s[k][4 * ty];
            f32x4 bf = *(const f32x4*)&b_s[k][4 * tx];
#pragma unroll
            for (int i = 0; i < 4; ++i)
#pragma unroll
                for (int j = 0; j < 4; ++j) acc[i][j] += af[i] * bf[j];
        }
    }
    f32x4 bi = *(const f32x4*)&b_ih[n0 + 4 * tx];
    f32x4 bh = *(const f32x4*)&b_hh[n0 + 4 * tx];
#pragma unroll
    for (int j = 0; j < 4; ++j) {
        const int n = n0 + 4 * tx + j;
        const float bias = bi[j] + bh[j];
        const int q = n >> 10, cidx = n & 1023;
        const int bg = cidx >> 2, r = cidx & 3;
#pragma unroll
        for (int i = 0; i < 4; ++i) {
            const int m = m0 + 4 * ty + i;
            gxT[((size_t)bg * T_STEPS + m) * 16 + q * 4 + r] = acc[i][j] + bias;
        }
    }
}

// ================= phase 2: persistent loop, whh in LDS =================
// 256 blocks x 256 threads, 1 block/CU. Wave w owns unit u = 4b+w.
// whh for the block's 4 units lives in LDS (64KB) — zero per-step global
// weight traffic, no register-allocator dependence (R1-R5 showed the
// allocator refuses >132 VGPRs, forcing a 64KB/CU/step L2 weight stream).
__global__ __launch_bounds__(256)
void lstm_loop(const float* __restrict__ W_hh,
               const float* __restrict__ h0,
               const float* __restrict__ c0,
               const float* __restrict__ gxT,
               float* __restrict__ out,
               unsigned long long* __restrict__ ring)
{
    __shared__ float whh_lds[16 * HDIM];   // [(w*4+q)][1024]
    __shared__ float h_lds[2][HDIM];

    const int tid = threadIdx.x;
    const int w   = tid >> 6;
    const int l   = tid & 63;
    const int u   = (blockIdx.x << 2) + w;

    // stage this block's 16 W_hh rows (4 units x 4 gates) into LDS
#pragma unroll
    for (int k = 0; k < 16; ++k) {
        const int c   = tid + (k << 8);     // chunk 0..4095 (f32x4 units)
        const int row = c >> 8;             // 0..15
        const int e4  = c & 255;
        const int ww  = row >> 2, q = row & 3;
        const int uu  = (blockIdx.x << 2) + ww;
        f32x4 v = *(const f32x4*)(W_hh + (size_t)(q * HDIM + uu) * HDIM + 4 * e4);
        *(f32x4*)&whh_lds[(ww * 4 + q) * HDIM + 4 * e4] = v;
    }

    float c = c0[u];
    f32x4 hr[4];
#pragma unroll
    for (int i = 0; i < 4; ++i) hr[i] = *(const f32x4*)(h0 + 4 * l + 256 * i);

    const float* gxb = gxT + (size_t)blockIdx.x * T_STEPS * 16;
    const int le = l & 15;
    float gxA = gxb[le];
    float gxB = gxb[16 + le];
    float gxC = 0.f;

    __syncthreads();   // weights staged

    const float* wl = &whh_lds[(w * 4) * HDIM + 4 * l];

    for (int t = 0; t < T_STEPS; ++t) {
        // gates = gx + whh(LDS) . h_{t-1}
        float acc[4];
#pragma unroll
        for (int q = 0; q < 4; ++q) {
            float a = 0.f;
#pragma unroll
            for (int i = 0; i < 4; ++i)
                a += dot4(*(const f32x4*)&wl[q * HDIM + 256 * i], hr[i]);
            acc[q] = a;
        }
#pragma unroll
        for (int m = 1; m < 64; m <<= 1) {
#pragma unroll
            for (int q = 0; q < 4; ++q) acc[q] += __shfl_xor(acc[q], m, 64);
        }
        const float gi = sigmoidf_(acc[0] + __shfl(gxA, 0 + w, 64));
        const float gf = sigmoidf_(acc[1] + __shfl(gxA, 4 + w, 64));
        const float gg = tanhf_   (acc[2] + __shfl(gxA, 8 + w, 64));
        const float go = sigmoidf_(acc[3] + __shfl(gxA, 12 + w, 64));
        c = gf * c + gi * gg;
        const float hval = go * tanhf_(c);

        if (l == 0) {
            const unsigned long long pk =
                ((unsigned long long)(unsigned)(t + 1) << 32) |
                (unsigned long long)__float_as_uint(hval);
            // publish (system scope); keeps "memory" so it can never sink
            // below the poll (publish-before-poll => no deadlock)
            asm volatile("global_store_dwordx2 %0, %1, off sc0 sc1"
                         :: "v"((unsigned long long)&ring[(t & 1) * HDIM + u]),
                            "v"(pk) : "memory");
            out[(size_t)t * HDIM + u] = hval;
        }
        if (t == T_STEPS - 1) break;

        // prefetch gx[t+2] (64B line, off critical path)
        {
            const int tn = (t + 2 < T_STEPS) ? (t + 2) : (T_STEPS - 1);
            gxC = gxb[(size_t)tn * 16 + le];
        }

        // wait for h_t: one 32B system-scope read per poll (no "memory"
        // clobber — LDS/global scheduling stays free; volatile keeps order)
        {
            const unsigned e = (unsigned)(t + 1);
            const unsigned long long base =
                (unsigned long long)(ring + (t & 1) * HDIM + 4 * tid);
            u32x4 p0, p1;
            for (;;) {
                asm volatile(
                    "global_load_dwordx4 %0, %2, off sc0 sc1\n\t"
                    "global_load_dwordx4 %1, %2, off offset:16 sc0 sc1\n\t"
                    "s_waitcnt vmcnt(0)"
                    : "=&v"(p0), "=&v"(p1)
                    : "v"(base));
                if (p0[1] == e && p0[3] == e && p1[1] == e && p1[3] == e) break;
            }
            const int ns = (t + 1) & 1;
            f32x4 hv;
            hv[0] = __uint_as_float(p0[0]);
            hv[1] = __uint_as_float(p0[2]);
            hv[2] = __uint_as_float(p1[0]);
            hv[3] = __uint_as_float(p1[2]);
            *(f32x4*)&h_lds[ns][4 * tid] = hv;
        }
        __syncthreads();
        {
            const int ns = (t + 1) & 1;
#pragma unroll
            for (int i = 0; i < 4; ++i)
                hr[i] = *(const f32x4*)&h_lds[ns][4 * l + 256 * i];
        }
        gxA = gxB; gxB = gxC;
    }
}

extern "C" void kernel_launch(void* const* d_in, const int* in_sizes, int n_in,
                              void* d_out, int out_size, void* d_ws, size_t ws_size,
                              hipStream_t stream)
{
    const float* x    = (const float*)d_in[0];
    const float* W_ih = (const float*)d_in[1];
    const float* W_hh = (const float*)d_in[2];
    const float* b_ih = (const float*)d_in[3];
    const float* b_hh = (const float*)d_in[4];
    const float* h0   = (const float*)d_in[5];
    const float* c0   = (const float*)d_in[6];

    unsigned long long* ring = (unsigned long long*)d_ws;
    float* gxT = (float*)((char*)d_ws + (1u << 20));

    hipMemsetAsync(d_ws, 0, 2 * HDIM * sizeof(unsigned long long), stream);
    gemm_gx<<<8192, 256, 0, stream>>>(x, W_ih, b_ih, b_hh, gxT);
    lstm_loop<<<256, 256, 0, stream>>>(W_hh, h0, c0, gxT, (float*)d_out, ring);
}